// Round 6
// baseline (209.473 us; speedup 1.0000x reference)
//
#include <hip/hip_runtime.h>
#include <stdint.h>

typedef unsigned short u16;
typedef __attribute__((ext_vector_type(8))) short short8;
typedef __attribute__((ext_vector_type(4))) short short4v;
typedef __attribute__((ext_vector_type(4))) float f32x4;

#define LOG2E 1.44269504088896340736f

#define Bb 8
#define NSEQ 1024
#define DIMC 768
#define NH 12
#define DH 64
#define INNER 768
#define MTOT (Bb*NSEQ)      /* 8192 */
#define QKVN (3*INNER)      /* 2304 */
#define HEADS_TOT (Bb*NH)   /* 96 */
#define QKV_PART ((size_t)Bb*NH*NSEQ*DH)

static __device__ inline u16 f2bf(float f) {
    uint32_t u = __builtin_bit_cast(uint32_t, f);
    uint32_t r = (u + 0x7fffu + ((u >> 16) & 1u)) >> 16;
    return (u16)r;
}

// pack two f32 -> bf16 pair (round-half-up) in 3 VALU ops via v_perm
static __device__ __forceinline__ uint32_t pkbf(float f0, float f1) {
    uint32_t u0 = __builtin_bit_cast(uint32_t, f0) + 0x8000u;
    uint32_t u1 = __builtin_bit_cast(uint32_t, f1) + 0x8000u;
    return __builtin_amdgcn_perm(u1, u0, 0x07060302u);
}

// 16x16x16 bf16 MFMA: B-operand k-packing matches 16x16 MFMA C-layout
#if __has_builtin(__builtin_amdgcn_mfma_f32_16x16x16bf16_1k)
static __device__ __forceinline__ f32x4 mfma16(short4v a, short4v b, f32x4 c) {
    return __builtin_amdgcn_mfma_f32_16x16x16bf16_1k(a, b, c, 0, 0, 0);
}
#else
static __device__ __forceinline__ f32x4 mfma16(short4v a, short4v b, f32x4 c) {
    asm volatile("v_mfma_f32_16x16x16_bf16 %0, %1, %2, %0\n\ts_nop 7\n\ts_nop 7"
                 : "+v"(c) : "v"(a), "v"(b));
    return c;
}
#endif

// ---- async global->LDS, 16B per lane ----
typedef __attribute__((address_space(1))) const void gas_void;
typedef __attribute__((address_space(3))) void las_void;
static __device__ __forceinline__ void async16(u16* lds, const u16* g) {
    __builtin_amdgcn_global_load_lds((gas_void*)(uintptr_t)g,
                                     (las_void*)(uintptr_t)lds, 16, 0, 0);
}

// ---------------- fused fp32 -> bf16 conversion (single dispatch) ----------------
#define NX8  786432
#define NWQ8 221184
#define NWP8 73728
#define NCVT (NX8 + NWQ8 + NWP8)
__global__ __launch_bounds__(256) void cvt_all(const float* __restrict__ x,
                                               const float* __restrict__ wq,
                                               const float* __restrict__ wp,
                                               u16* __restrict__ xb,
                                               u16* __restrict__ wqb,
                                               u16* __restrict__ wpb) {
    int i = blockIdx.x * 256 + threadIdx.x;
    const float* s; u16* d; int j;
    if (i < NX8) { s = x; d = xb; j = i; }
    else if (i < NX8 + NWQ8) { s = wq; d = wqb; j = i - NX8; }
    else { s = wp; d = wpb; j = i - NX8 - NWQ8; }
    const float4* s4 = (const float4*)s;
    float4 a = s4[2 * j], b = s4[2 * j + 1];
    float v[8] = {a.x, a.y, a.z, a.w, b.x, b.y, b.z, b.w};
    u16 o[8];
#pragma unroll
    for (int t = 0; t < 8; t++) o[t] = f2bf(v[t]);
    ((uint4*)d)[j] = *(const uint4*)o;
}

// ---------------- QKV GEMM: 512 thr, 128x256, BK=64, 2-barrier single buffer --------
// LDS rows are 128B = 8 chunks of 16B; chunk (r,c) stored at slot r*8 + ((c+r)&7).
#define BK 64
__global__ __launch_bounds__(512, 4) void gemm_qkv(const u16* __restrict__ A,
                                                   const u16* __restrict__ Bm,
                                                   u16* __restrict__ qkv) {
    __shared__ u16 As[128 * BK];   // 16 KB
    __shared__ u16 Bs[256 * BK];   // 32 KB
    const int tid = threadIdx.x;
    const int w = tid >> 6, lane = tid & 63, quad = lane >> 4, l16 = lane & 15;
    const int wr = w >> 2, wc = w & 3;
    const int bid = blockIdx.x + 9 * blockIdx.y;
    const int xcd = bid & 7, slot = bid >> 3;
    const int m0 = (xcd + 8 * (slot / 9)) * 128;
    const int n0 = (slot % 9) * 256;
    const int K = DIMC;

    const int rl8 = lane >> 3, cc8 = lane & 7;
    const u16* agp[2]; int asl[2];
#pragma unroll
    for (int j = 0; j < 2; j++) {
        int r = w * 16 + j * 8 + rl8;
        agp[j] = A + (size_t)(m0 + r) * K + ((cc8 - r) & 7) * 8;
        asl[j] = (w * 16 + j * 8) * BK;
    }
    const u16* bgp[4]; int bsl[4];
#pragma unroll
    for (int j = 0; j < 4; j++) {
        int r = w * 32 + j * 8 + rl8;
        bgp[j] = Bm + (size_t)(n0 + r) * K + ((cc8 - r) & 7) * 8;
        bsl[j] = (w * 32 + j * 8) * BK;
    }

    int abase[4], bbase[4], sw[2];
#pragma unroll
    for (int t = 0; t < 4; t++) {
        abase[t] = (wr * 64 + t * 16 + l16) * BK;
        bbase[t] = (wc * 64 + t * 16 + l16) * BK;
    }
#pragma unroll
    for (int kc = 0; kc < 2; kc++) sw[kc] = ((quad + 4 * kc + l16) & 7) * 8;

    f32x4 acc[4][4] = {};
    for (int kt = 0; kt < K; kt += BK) {
        __syncthreads();   // prev iter's fragment reads complete (WAR)
#pragma unroll
        for (int j = 0; j < 2; j++) async16(As + asl[j], agp[j] + kt);
#pragma unroll
        for (int j = 0; j < 4; j++) async16(Bs + bsl[j], bgp[j] + kt);
        __syncthreads();   // drain staging
#pragma unroll
        for (int kc = 0; kc < 2; kc++) {
            short8 af[4], bf[4];
#pragma unroll
            for (int t = 0; t < 4; t++) af[t] = *(const short8*)(As + abase[t] + sw[kc]);
#pragma unroll
            for (int t = 0; t < 4; t++) bf[t] = *(const short8*)(Bs + bbase[t] + sw[kc]);
#pragma unroll
            for (int mt = 0; mt < 4; mt++)
#pragma unroll
                for (int nt = 0; nt < 4; nt++)
                    acc[mt][nt] = __builtin_amdgcn_mfma_f32_16x16x32_bf16(af[mt], bf[nt],
                                                                          acc[mt][nt], 0, 0, 0);
        }
    }

#pragma unroll
    for (int nt = 0; nt < 4; nt++) {
        int o = n0 + wc * 64 + nt * 16 + l16;
        int which = o / 768;
        int rem = o - which * 768;
        int h = rem >> 6, d = rem & 63;
        if (which == 2) {
            u16* vt = qkv + 2 * QKV_PART;
#pragma unroll
            for (int mt = 0; mt < 4; mt++) {
                int m = m0 + wr * 64 + mt * 16 + quad * 4;
                int bb = m >> 10, ns = m & 1023;
                alignas(8) u16 pk[4];
#pragma unroll
                for (int r = 0; r < 4; r++) pk[r] = f2bf(acc[mt][nt][r]);
                *(uint2*)(vt + ((size_t)(bb * NH + h) * DH + d) * NSEQ + ns) =
                    *(const uint2*)pk;
            }
        } else {
            float sc = (which == 0) ? (0.125f * LOG2E) : 1.0f;
#pragma unroll
            for (int mt = 0; mt < 4; mt++)
#pragma unroll
                for (int r = 0; r < 4; r++) {
                    int m = m0 + wr * 64 + mt * 16 + quad * 4 + r;
                    int bb = m >> 10, ns = m & 1023;
                    size_t idx = (size_t)which * QKV_PART +
                                 (((size_t)(bb * NH + h) * NSEQ + ns) << 6) + d;
                    qkv[idx] = f2bf(acc[mt][nt][r] * sc);
                }
        }
    }
}

// ---------------- proj GEMM: 256 thr, 128x128, BK=64, 2-barrier single buffer --------
__global__ __launch_bounds__(256) void gemm_proj(const u16* __restrict__ A,
                                                 const u16* __restrict__ Bm,
                                                 float* __restrict__ Co) {
    __shared__ u16 As[128 * BK];
    __shared__ u16 Bs[128 * BK];
    const int tid = threadIdx.x;
    const int w = tid >> 6, lane = tid & 63, quad = lane >> 4, l16 = lane & 15;
    const int wr = w >> 1, wc = w & 1;
    const int bid = blockIdx.x + 6 * blockIdx.y;
    const int xcd = bid & 7, slot = bid >> 3;
    const int m0 = (xcd + 8 * (slot / 6)) * 128;
    const int n0 = (slot % 6) * 128;
    const int K = INNER, N = DIMC;

    const int rl8 = lane >> 3, cc8 = lane & 7;
    const u16* agp[4]; const u16* bgp[4]; int asl[4];
#pragma unroll
    for (int j = 0; j < 4; j++) {
        int r = w * 32 + j * 8 + rl8;
        int c = ((cc8 - r) & 7) * 8;
        agp[j] = A + (size_t)(m0 + r) * K + c;
        bgp[j] = Bm + (size_t)(n0 + r) * K + c;
        asl[j] = (w * 32 + j * 8) * BK;
    }

    int abase[4], bbase[4], sw[2];
#pragma unroll
    for (int t = 0; t < 4; t++) {
        abase[t] = (wr * 64 + t * 16 + l16) * BK;
        bbase[t] = (wc * 64 + t * 16 + l16) * BK;
    }
#pragma unroll
    for (int kc = 0; kc < 2; kc++) sw[kc] = ((quad + 4 * kc + l16) & 7) * 8;

    f32x4 acc[4][4] = {};
    for (int kt = 0; kt < K; kt += BK) {
        __syncthreads();
#pragma unroll
        for (int j = 0; j < 4; j++) {
            async16(As + asl[j], agp[j] + kt);
            async16(Bs + asl[j], bgp[j] + kt);
        }
        __syncthreads();
#pragma unroll
        for (int kc = 0; kc < 2; kc++) {
            short8 af[4], bf[4];
#pragma unroll
            for (int t = 0; t < 4; t++) af[t] = *(const short8*)(As + abase[t] + sw[kc]);
#pragma unroll
            for (int t = 0; t < 4; t++) bf[t] = *(const short8*)(Bs + bbase[t] + sw[kc]);
#pragma unroll
            for (int mt = 0; mt < 4; mt++)
#pragma unroll
                for (int nt = 0; nt < 4; nt++)
                    acc[mt][nt] = __builtin_amdgcn_mfma_f32_16x16x32_bf16(af[mt], bf[nt],
                                                                          acc[mt][nt], 0, 0, 0);
        }
    }
#pragma unroll
    for (int mt = 0; mt < 4; mt++)
#pragma unroll
        for (int nt = 0; nt < 4; nt++) {
            int o = n0 + wc * 64 + nt * 16 + l16;
#pragma unroll
            for (int r = 0; r < 4; r++) {
                int m = m0 + wr * 64 + mt * 16 + quad * 4 + r;
                Co[(size_t)m * N + o] = acc[mt][nt][r];
            }
        }
}

// ---------------- Flash attention v6: 128-key tiles, 2-barrier, co-XCD heads --------
// grid (96 bh, 8 qt). Ks: 128 key-rows x 64 d (rows 128B, rot &7).
// Vs: 64 d-rows x 128 keys (rows 256B, 16 chunks, rot &15).
__global__ __launch_bounds__(256) void attn_kernel(const u16* __restrict__ qkv,
                                                   u16* __restrict__ attn) {
    __shared__ u16 Ks[128 * 64];   // 16 KB
    __shared__ u16 Vs[64 * 128];   // 16 KB

    const int tid = threadIdx.x;
    const int w = tid >> 6, lane = tid & 63, quad = lane >> 4, l16 = lane & 15;
    const int bh = blockIdx.x, qt = blockIdx.y;
    const size_t headoff = (size_t)bh * NSEQ * DH;
    const u16* Qp = qkv + headoff;
    const u16* Kp = qkv + QKV_PART + headoff;
    const u16* Vtp = qkv + 2 * QKV_PART + headoff;
    const int q0 = qt * 128 + w * 32;

    // K staging: 4 async16/wave, rows w*32 + j*8 + (lane>>3)
    const int rl8 = lane >> 3, cc8 = lane & 7;
    const u16* kg[4]; int ksl[4];
#pragma unroll
    for (int j = 0; j < 4; j++) {
        int r = w * 32 + j * 8 + rl8;
        kg[j] = Kp + (size_t)r * DH + ((cc8 - r) & 7) * 8;
        ksl[j] = (w * 32 + j * 8) * 64;
    }
    // V staging: 4 async16/wave, rows w*16 + j*4 + quad (256B rows), chunk lane&15
    const int cc16 = lane & 15;
    const u16* vg[4]; int vsl[4];
#pragma unroll
    for (int j = 0; j < 4; j++) {
        int r = w * 16 + j * 4 + quad;
        vg[j] = Vtp + (size_t)r * NSEQ + ((cc16 - r) & 15) * 8;
        vsl[j] = (w * 16 + j * 4) * 128;
    }

    const int sw0 = ((quad + l16) & 7) * 8;
    const int sw1 = ((quad + 4 + l16) & 7) * 8;

    short8 qf[2][2];
#pragma unroll
    for (int mf = 0; mf < 2; mf++) {
        qf[mf][0] = *(const short8*)(Qp + (size_t)(q0 + mf * 16 + l16) * DH + quad * 8);
        qf[mf][1] = *(const short8*)(Qp + (size_t)(q0 + mf * 16 + l16) * DH + 32 + quad * 8);
    }

    f32x4 oacc[2][4] = {};
    float lsum[2] = {0.f, 0.f};

    for (int kt = 0; kt < NSEQ; kt += 128) {
        __syncthreads();   // prev iter's fragment reads complete (WAR)
#pragma unroll
        for (int j = 0; j < 4; j++) {
            async16(Ks + ksl[j], kg[j] + (size_t)kt * DH);
            async16(Vs + vsl[j], vg[j] + kt);
        }
        __syncthreads();   // drain staging

#pragma unroll
        for (int half = 0; half < 2; half++) {
            short8 kf[4][2];
#pragma unroll
            for (int nt = 0; nt < 4; nt++) {
                const u16* kr = Ks + (half * 64 + nt * 16 + l16) * 64;
                kf[nt][0] = *(const short8*)(kr + sw0);
                kf[nt][1] = *(const short8*)(kr + sw1);
            }
            short4v vf[4][4];
#pragma unroll
            for (int nt2 = 0; nt2 < 4; nt2++) {
                int row = nt2 * 16 + l16;
#pragma unroll
                for (int c = 0; c < 4; c++) {
                    int chunk = half * 8 + c * 2 + (quad >> 1);
                    int off = row * 128 + (((chunk + row) & 15) << 3) + (quad & 1) * 4;
                    vf[nt2][c] = *(const short4v*)(Vs + off);
                }
            }

#pragma unroll
            for (int mf = 0; mf < 2; mf++) {
                f32x4 st[4];
#pragma unroll
                for (int nt = 0; nt < 4; nt++) {
                    f32x4 z = {};
                    z = __builtin_amdgcn_mfma_f32_16x16x32_bf16(kf[nt][0], qf[mf][0], z, 0, 0, 0);
                    z = __builtin_amdgcn_mfma_f32_16x16x32_bf16(kf[nt][1], qf[mf][1], z, 0, 0, 0);
                    st[nt] = z;
                }
                short4v pf[4];
#pragma unroll
                for (int c = 0; c < 4; c++) {
                    float p0 = __builtin_amdgcn_exp2f(st[c][0]);
                    float p1 = __builtin_amdgcn_exp2f(st[c][1]);
                    float p2 = __builtin_amdgcn_exp2f(st[c][2]);
                    float p3 = __builtin_amdgcn_exp2f(st[c][3]);
                    lsum[mf] += (p0 + p1) + (p2 + p3);
                    uint2 u = {pkbf(p0, p1), pkbf(p2, p3)};
                    pf[c] = __builtin_bit_cast(short4v, u);
                }
#pragma unroll
                for (int nt2 = 0; nt2 < 4; nt2++)
#pragma unroll
                    for (int c = 0; c < 4; c++)
                        oacc[mf][nt2] = mfma16(vf[nt2][c], pf[c], oacc[mf][nt2]);
            }
        }
    }

#pragma unroll
    for (int mf = 0; mf < 2; mf++) {
        float v = lsum[mf];
        v += __shfl_xor(v, 16);
        v += __shfl_xor(v, 32);
        lsum[mf] = 1.0f / v;
    }

    const int b = bh / NH, h = bh - (bh / NH) * NH;
#pragma unroll
    for (int mf = 0; mf < 2; mf++) {
        int q = q0 + mf * 16 + l16;
        float inv = lsum[mf];
#pragma unroll
        for (int nt2 = 0; nt2 < 4; nt2++) {
            uint2 u = {pkbf(oacc[mf][nt2][0] * inv, oacc[mf][nt2][1] * inv),
                       pkbf(oacc[mf][nt2][2] * inv, oacc[mf][nt2][3] * inv)};
            int d = nt2 * 16 + quad * 4;
            *(uint2*)(attn + ((size_t)(b * NSEQ + q)) * INNER + h * DH + d) = u;
        }
    }
}

extern "C" void kernel_launch(void* const* d_in, const int* in_sizes, int n_in,
                              void* d_out, int out_size, void* d_ws, size_t ws_size,
                              hipStream_t stream) {
    const float* x = (const float*)d_in[0];
    const float* w_qkv = (const float*)d_in[1];
    const float* w_proj = (const float*)d_in[2];
    float* out = (float*)d_out;

    u16* xb = (u16*)d_ws;
    u16* wqkvb = xb + 6291456;
    u16* wprojb = wqkvb + 1769472;
    u16* qkvb = wprojb + 589824;
    u16* attnb = qkvb + 18874368;

    cvt_all<<<NCVT / 256, 256, 0, stream>>>(x, w_qkv, w_proj, xb, wqkvb, wprojb);

    dim3 g1(QKVN / 256, MTOT / 128);   // (9, 64), 512 threads
    gemm_qkv<<<g1, 512, 0, stream>>>(xb, wqkvb, qkvb);

    dim3 g2(HEADS_TOT, NSEQ / 128);    // (96, 8) — same-head blocks co-XCD
    attn_kernel<<<g2, 256, 0, stream>>>(qkvb, attnb);

    dim3 g3(INNER / 128, MTOT / 128);  // (6, 64)
    gemm_proj<<<g3, 256, 0, stream>>>(attnb, wprojb, out);
}